// Round 5
// baseline (345.961 us; speedup 1.0000x reference)
//
#include <hip/hip_runtime.h>

typedef unsigned short u16;
typedef __attribute__((ext_vector_type(4))) unsigned int u32x4;
typedef __attribute__((ext_vector_type(4))) float f32x4;
typedef __attribute__((ext_vector_type(8))) short s16x8;

#define B_ 8
#define T_ 2048
#define C_ 1024
#define H_ 16
#define HS_ 64
#define CHUNK_ 256
#define NC_ 8

union U8 { u32x4 u; u16 h[8]; };

__device__ __forceinline__ float b2f(u16 v) {
    union { unsigned int i; float f; } c; c.i = ((unsigned int)v) << 16; return c.f;
}
__device__ __forceinline__ u16 f2b(float f) {
    union { float f; unsigned int i; } c; c.f = f;
    unsigned int i = c.i;
    return (u16)((i + 0x7FFFu + ((i >> 16) & 1u)) >> 16);  // RNE
}
// fast sigmoid: v_exp_f32 + v_rcp_f32 (args here are tiny, ~0.02 — no range issues)
__device__ __forceinline__ float fsig(float z) {
    return __builtin_amdgcn_rcpf(1.f + __expf(-z));
}

// async 16B global->LDS (lds dest = wave-uniform base + lane*16)
typedef __attribute__((address_space(1))) void GV;
typedef __attribute__((address_space(3))) void LV;
__device__ __forceinline__ void glds16(const void* g, void* l) {
    __builtin_amdgcn_global_load_lds((GV*)g, (LV*)l, 16, 0, 0);
}

// ---------------- K0: f32 -> bf16 conversion of the 4 weight matrices ------
__global__ __launch_bounds__(256) void cvt4_kernel(
    const float* __restrict__ s0, const float* __restrict__ s1,
    const float* __restrict__ s2, const float* __restrict__ s3,
    u16* __restrict__ dst)
{
    int i = blockIdx.x * 256 + threadIdx.x;   // 4 * 131072 threads, 8 elems each
    int m = i >> 17;
    const float* s = (m == 0) ? s0 : (m == 1) ? s1 : (m == 2) ? s2 : s3;
    size_t j = (size_t)(i & 131071) * 8;
    f32x4 a = *reinterpret_cast<const f32x4*>(s + j);
    f32x4 b = *reinterpret_cast<const f32x4*>(s + j + 4);
    U8 o;
    #pragma unroll
    for (int k = 0; k < 4; k++) { o.h[k] = f2b(a[k]); o.h[4 + k] = f2b(b[k]); }
    *reinterpret_cast<u32x4*>(dst + (size_t)m * C_ * C_ + j) = o.u;
}

// ---------------- K1: gate + time-shift + maa mix, 4-row t-strip ------------
// strip=4 -> 524288 threads / 2048 blocks: full occupancy for this
// latency-sensitive streaming kernel (was strip=8 / 1024 blocks, 41% HBM).
__global__ __launch_bounds__(256) void mix_kernel(
    const float* __restrict__ x, const float* __restrict__ vol,
    const float* __restrict__ Wvol, const float* __restrict__ bvol,
    const float* __restrict__ mk, const float* __restrict__ mv, const float* __restrict__ mr,
    u16* __restrict__ xk, u16* __restrict__ xv, u16* __restrict__ xr)
{
    int idx = blockIdx.x * 256 + threadIdx.x;      // B*(T/4)*(C/8) threads
    int c0 = (idx & 127) * 8;
    int bt4 = idx >> 7;
    int t0  = (bt4 & 511) * 4;
    int b   = bt4 >> 9;
    size_t rowOff = ((size_t)b * T_ + t0) * C_ + c0;

    float wv[8], bv[8], mkv[8], mvv[8], mrv[8];
    #pragma unroll
    for (int j = 0; j < 8; j += 4) {
        f32x4 a;
        a = *reinterpret_cast<const f32x4*>(Wvol + c0 + j);
        wv[j] = a[0]; wv[j+1] = a[1]; wv[j+2] = a[2]; wv[j+3] = a[3];
        a = *reinterpret_cast<const f32x4*>(bvol + c0 + j);
        bv[j] = a[0]; bv[j+1] = a[1]; bv[j+2] = a[2]; bv[j+3] = a[3];
        a = *reinterpret_cast<const f32x4*>(mk + c0 + j);
        mkv[j] = a[0]; mkv[j+1] = a[1]; mkv[j+2] = a[2]; mkv[j+3] = a[3];
        a = *reinterpret_cast<const f32x4*>(mv + c0 + j);
        mvv[j] = a[0]; mvv[j+1] = a[1]; mvv[j+2] = a[2]; mvv[j+3] = a[3];
        a = *reinterpret_cast<const f32x4*>(mr + c0 + j);
        mrv[j] = a[0]; mrv[j+1] = a[1]; mrv[j+2] = a[2]; mrv[j+3] = a[3];
    }

    const float* volb = vol + (size_t)b * T_;
    float gp[8];
    if (t0 == 0) {
        #pragma unroll
        for (int j = 0; j < 8; j++) gp[j] = 0.f;
    } else {
        float vp = volb[t0 - 1];
        #pragma unroll
        for (int j = 0; j < 8; j += 4) {
            f32x4 a = *reinterpret_cast<const f32x4*>(x + rowOff - C_ + j);
            gp[j]   = a[0] * fsig(vp * wv[j]   + bv[j]);
            gp[j+1] = a[1] * fsig(vp * wv[j+1] + bv[j+1]);
            gp[j+2] = a[2] * fsig(vp * wv[j+2] + bv[j+2]);
            gp[j+3] = a[3] * fsig(vp * wv[j+3] + bv[j+3]);
        }
    }

    #pragma unroll
    for (int s = 0; s < 4; s++) {
        float vc = volb[t0 + s];
        size_t off = rowOff + (size_t)s * C_;
        float g[8];
        #pragma unroll
        for (int j = 0; j < 8; j += 4) {
            f32x4 a = *reinterpret_cast<const f32x4*>(x + off + j);
            g[j]   = a[0] * fsig(vc * wv[j]   + bv[j]);
            g[j+1] = a[1] * fsig(vc * wv[j+1] + bv[j+1]);
            g[j+2] = a[2] * fsig(vc * wv[j+2] + bv[j+2]);
            g[j+3] = a[3] * fsig(vc * wv[j+3] + bv[j+3]);
        }
        U8 ok, ov, orr;
        #pragma unroll
        for (int j = 0; j < 8; j++) {
            float xx = gp[j] - g[j];
            ok.h[j]  = f2b(g[j] + xx * mkv[j]);
            ov.h[j]  = f2b(g[j] + xx * mvv[j]);
            orr.h[j] = f2b(g[j] + xx * mrv[j]);
            gp[j] = g[j];
        }
        *reinterpret_cast<u32x4*>(xk + off) = ok.u;
        *reinterpret_cast<u32x4*>(xv + off) = ov.u;
        *reinterpret_cast<u32x4*>(xr + off) = orr.u;
    }
}

// ---------------- K2: C = A @ W^T  (8-phase schedule) -----------------------
// MODE 0: f32 row-major; MODE 1: bf16 row-major; MODE 2: bf16 PACKED-TILE
// transposed layout PKT: for (c,t): idx = ((c>>4)*512 + (t>>5))*512
// + (c&15)*32 + (t&31). Each 16c x 32t tile = 1 KB contiguous -> both the
// epilogue stores and kvscan's fragment loads are full-line streams.
#define GBM_ 256
#define GBN_ 256
#define GBK_ 64
#define GK_  1024
#define GNT_ 16                    // GK_/GBK_
#define GEMM_LDS_BYTES 131072      // 2 * (256*64 + 256*64) * 2B

template<int MODE>
__global__ __launch_bounds__(512, 2) void gemm_bt(
    const u16* __restrict__ A, const u16* __restrict__ W, void* __restrict__ Cc)
{
    extern __shared__ __align__(16) u16 lds[];
    const int tid  = threadIdx.x;
    const int lane = tid & 63, w = tid >> 6;
    const int r16  = lane & 15, quad = lane >> 4;
    const int wm2  = w >> 2;         // 0..1 : M-half (128 rows)
    const int wn4  = w & 3;          // 0..3 : N-quarter (64 cols)
    const int id   = blockIdx.x;
    const int bm   = id & 63, bn = id >> 6;

    const u16* Ab = A + (size_t)bm * GBM_ * GK_;
    const u16* Wb = W + (size_t)bn * GBN_ * GK_;

    // stage source (pre-swizzled): wave w owns rows [w*16, w*16+16) of each
    // 128-row half; lane -> row_in_8 = lane>>3, global chunk = (lane&7)^(lane>>3)
    const int srow8  = lane >> 3;
    const int schunk = ((lane & 7) ^ srow8) * 8;            // elems
    const u16* aSrc = Ab + (size_t)(w * 16 + srow8) * GK_ + schunk;
    const u16* bSrc = Wb + (size_t)(w * 16 + srow8) * GK_ + schunk;

    // fragment read bases (u16 elems). LDS row pitch = 64 elems (128 B).
    const int fA0 = (wm2 * 128 + r16) * 64;
    const int fB0 = 16384 + (wn4 * 64 + r16) * 64;
    const int c0 = ((quad)     ^ (r16 & 7)) * 8;            // ks=0 chunk ofs
    const int c1 = ((quad | 4) ^ (r16 & 7)) * 8;            // ks=1 chunk ofs

    f32x4 acc[8][4];
    #pragma unroll
    for (int mi = 0; mi < 8; mi++)
        #pragma unroll
        for (int ni = 0; ni < 4; ni++)
            acc[mi][ni] = f32x4{0.f, 0.f, 0.f, 0.f};

#define STQ(tt, h) do {                                                       \
    const size_t ko_ = (size_t)(tt) * 64;                                     \
    u16* db_ = lds + (((tt) & 1) * 32768) + ((h) * 128 + w * 16) * 64;        \
    glds16(aSrc + (size_t)((h) * 128)     * GK_ + ko_, db_);                  \
    glds16(aSrc + (size_t)((h) * 128 + 8) * GK_ + ko_, db_ + 512);            \
    glds16(bSrc + (size_t)((h) * 128)     * GK_ + ko_, db_ + 16384);          \
    glds16(bSrc + (size_t)((h) * 128 + 8) * GK_ + ko_, db_ + 16384 + 512);    \
} while (0)

#define PH_BAR() do { asm volatile("" ::: "memory");                          \
    __builtin_amdgcn_s_barrier(); asm volatile("" ::: "memory"); } while (0)
#define PH_LGKM0() do { asm volatile("s_waitcnt lgkmcnt(0)" ::: "memory");    \
    __builtin_amdgcn_sched_barrier(0); } while (0)
#define LDFA(CO) { _Pragma("unroll") for (int mi = 0; mi < 8; mi++)           \
    fa[mi] = *reinterpret_cast<const s16x8*>(lds + pb + fA0 + mi * 1024 + (CO)); }
#define LDFB(NH, CO) { _Pragma("unroll") for (int ni = 0; ni < 2; ni++)       \
    fb[ni] = *reinterpret_cast<const s16x8*>(lds + pb + fB0 + ((NH) * 2 + ni) * 1024 + (CO)); }
#define MFMA16(NH) do { __builtin_amdgcn_s_setprio(1);                        \
    _Pragma("unroll") for (int mi = 0; mi < 8; mi++) {                        \
        acc[mi][(NH)*2+0] = __builtin_amdgcn_mfma_f32_16x16x32_bf16(          \
            fa[mi], fb[0], acc[mi][(NH)*2+0], 0, 0, 0);                       \
        acc[mi][(NH)*2+1] = __builtin_amdgcn_mfma_f32_16x16x32_bf16(          \
            fa[mi], fb[1], acc[mi][(NH)*2+1], 0, 0, 0);                       \
    } __builtin_amdgcn_s_setprio(0); } while (0)

    // prologue: stage both halves of tile 0, drain once, barrier
    STQ(0, 0);
    STQ(0, 1);
    asm volatile("s_waitcnt vmcnt(0)" ::: "memory");
    PH_BAR();

    for (int t = 0; t < GNT_; ++t) {
        const int pb = (t & 1) * 32768;
        s16x8 fa[8], fb[2];
        // ---- ph0: (ks0, nh0) — 10 reads + stage BOTH halves of t+1
        //      (moved H1 here from ph2: ph3's vmcnt(0) slack grows to ~3.5
        //       phases, covering L3/HBM latency)
        LDFA(c0); LDFB(0, c0);
        if (t + 1 < GNT_) { STQ(t + 1, 0); STQ(t + 1, 1); }
        PH_BAR(); PH_LGKM0(); MFMA16(0); PH_BAR();
        // ---- ph1: (ks0, nh1) — 2 reads, reuse fa
        LDFB(1, c0);
        PH_BAR(); PH_LGKM0(); MFMA16(1); PH_BAR();
        // ---- ph2: (ks1, nh0) — 10 reads
        LDFA(c1); LDFB(0, c1);
        PH_BAR(); PH_LGKM0(); MFMA16(0); PH_BAR();
        // ---- ph3: (ks1, nh1) — 2 reads; tile-end vmcnt(0)
        LDFB(1, c1);
        PH_BAR(); PH_LGKM0(); MFMA16(1);
        asm volatile("s_waitcnt vmcnt(0)" ::: "memory");
        PH_BAR();
    }
#undef STQ
#undef LDFA
#undef LDFB
#undef MFMA16
#undef PH_LGKM0
#undef PH_BAR

    if constexpr (MODE == 0) {
        // f32: 16 lanes * 4B = 64B full lines — direct store
        float* C = (float*)Cc;
        #pragma unroll
        for (int mi = 0; mi < 8; mi++) {
            int row0 = bm * GBM_ + wm2 * 128 + mi * 16 + quad * 4;
            #pragma unroll
            for (int ni = 0; ni < 4; ni++) {
                int col = bn * GBN_ + wn4 * 64 + ni * 16 + r16;
                #pragma unroll
                for (int i = 0; i < 4; i++)
                    C[(size_t)(row0 + i) * C_ + col] = acc[mi][ni][i];
            }
        }
    } else if constexpr (MODE == 1) {
        // bf16 row-major: per-wave LDS patch [64][72] -> 128B-row dwordx4 stores
        u16* ep = lds + w * 4608;
        u16* C = (u16*)Cc;
        #pragma unroll
        for (int half = 0; half < 2; half++) {
            #pragma unroll
            for (int mi2 = 0; mi2 < 4; mi2++) {
                int mi = half * 4 + mi2;
                #pragma unroll
                for (int ni = 0; ni < 4; ni++)
                    #pragma unroll
                    for (int i = 0; i < 4; i++)
                        ep[(mi2 * 16 + quad * 4 + i) * 72 + ni * 16 + r16] =
                            f2b(acc[mi][ni][i]);
            }
            asm volatile("s_waitcnt lgkmcnt(0)" ::: "memory");
            __builtin_amdgcn_sched_barrier(0);
            #pragma unroll
            for (int it = 0; it < 8; it++) {
                int rr = it * 8 + (lane >> 3);
                u32x4 val = *reinterpret_cast<const u32x4*>(ep + rr * 72 + (lane & 7) * 8);
                size_t grow = (size_t)(bm * GBM_ + wm2 * 128 + half * 64 + rr);
                *reinterpret_cast<u32x4*>(
                    C + grow * C_ + bn * GBN_ + wn4 * 64 + (lane & 7) * 8) = val;
            }
            asm volatile("s_waitcnt vmcnt(0) lgkmcnt(0)" ::: "memory");
        }
    } else {
        // MODE 2: bf16 PKT. Per-wave LDS patch [64 cols][16 chunks of 8 rows],
        // chunk XOR-swizzled by col. Each store instr writes one FULL 1 KB
        // packed tile (64 lanes x 16B contiguous).
        u16* ep = lds + w * 8192;
        #pragma unroll
        for (int mi = 0; mi < 8; mi++) {
            const int chunk = mi * 2 + (quad >> 1);
            const int rsub = (quad & 1) * 4;
            #pragma unroll
            for (int ni = 0; ni < 4; ni++) {
                const int col = ni * 16 + r16;
                u16* p = ep + col * 128 + ((chunk ^ col) & 15) * 8 + rsub;
                p[0] = f2b(acc[mi][ni][0]);
                p[1] = f2b(acc[mi][ni][1]);
                p[2] = f2b(acc[mi][ni][2]);
                p[3] = f2b(acc[mi][ni][3]);
            }
        }
        asm volatile("s_waitcnt lgkmcnt(0)" ::: "memory");
        __builtin_amdgcn_sched_barrier(0);
        u16* C = (u16*)Cc;
        const int cl = lane >> 2, ch4 = lane & 3;
        const int gc0 = bn * 16 + wn4 * 4;       // c-group base (c>>4)
        const int tt0 = bm * 8 + wm2 * 4;        // t-tile base (t>>5)
        #pragma unroll
        for (int it = 0; it < 16; it++) {
            const int col_l = (it & 3) * 16 + cl;
            const int chunk = (it >> 2) * 4 + ch4;
            u32x4 val = *reinterpret_cast<const u32x4*>(
                ep + col_l * 128 + ((chunk ^ col_l) & 15) * 8);
            const size_t tile = (size_t)(gc0 + (it & 3)) * 512 + tt0 + (it >> 2);
            *reinterpret_cast<u32x4*>(C + tile * 512 + cl * 32 + ch4 * 8) = val;
        }
    }
}

// ---------------- K3: fused P = v^T k + decay scan (LDS-staged v2) ----------
// Inputs in PKT packed layout. One block per (b,h,m-half), 512 threads
// (8 waves: 4 n-groups x 2 m-sub), LDS 96 KB = 2 x 48 KiB {v 32K, k 16K}.
// Per j: stage j+1's 48 x 1KB tiles via glds16 (issue-early / wait-late:
// vmcnt(0) at top of next j = ~full-iteration slack), one barrier per j,
// 8 MFMA/wave from LDS, scan state in regs, bf16 stT store.
#define KVS_LDS_BYTES 98304

__global__ __launch_bounds__(512) void kvscan_kernel(
    const u16* __restrict__ kT, const u16* __restrict__ vT,
    const float* __restrict__ td, u16* __restrict__ stT)
{
    extern __shared__ __align__(16) u16 klds[];
    const int bm2 = blockIdx.x;            // bh*2 + mh
    const int mh = bm2 & 1, bh = bm2 >> 1;
    const int h = bh & (H_ - 1), b = bh >> 4;
    const float wdec = expf(-expf(td[h]));
    const int tid = threadIdx.x, lane = tid & 63, w = tid >> 6;
    const int r16 = lane & 15, quad = lane >> 4;
    const int cgn = w >> 1;                // n-group 0..3 (16 rows)
    const int ck  = w & 1;                 // m-sub 0..1 (16 cols)
    const int tt0 = b * 64;                // t-tile base for this batch
    const int loff = r16 * 32 + quad * 8;  // lane offset within a 1KB tile

    // stage: 48 tiles (tau<32: v cgroup tau>>3, ks tau&7; else k)
#define KSTG(jj, bb) do {                                                     \
    u16* db_ = klds + (bb) * 24576;                                           \
    _Pragma("unroll")                                                         \
    for (int q = 0; q < 6; q++) {                                             \
        const int tau = w * 6 + q;                                            \
        const u16* src;                                                       \
        if (tau < 32)                                                         \
            src = vT + ((size_t)(h * 4 + (tau >> 3)) * 512 +                  \
                        tt0 + (jj) * 8 + (tau & 7)) * 512;                    \
        else                                                                  \
            src = kT + ((size_t)(h * 4 + mh * 2 + ((tau - 32) >> 3)) * 512 +  \
                        tt0 + (jj) * 8 + ((tau - 32) & 7)) * 512;             \
        glds16(src + (size_t)lane * 8, db_ + tau * 512);                      \
    }                                                                         \
} while (0)

    KSTG(0, 0);

    f32x4 st = f32x4{0.f, 0.f, 0.f, 0.f};
    for (int j = 0; j < NC_; ++j) {
        asm volatile("s_waitcnt vmcnt(0)" ::: "memory");
        __syncthreads();
        if (j + 1 < NC_) KSTG(j + 1, (j + 1) & 1);
        const u16* bb = klds + (j & 1) * 24576;
        f32x4 acc = f32x4{0.f, 0.f, 0.f, 0.f};
        #pragma unroll
        for (int ks = 0; ks < 8; ks++) {
            s16x8 fa = *reinterpret_cast<const s16x8*>(
                bb + (cgn * 8 + ks) * 512 + loff);
            s16x8 fb = *reinterpret_cast<const s16x8*>(
                bb + (32 + ck * 8 + ks) * 512 + loff);
            acc = __builtin_amdgcn_mfma_f32_16x16x32_bf16(fa, fb, acc, 0, 0, 0);
        }
        st = (st + acc) * wdec;
        u16* out = stT + ((size_t)bh * NC_ + j) * 4096;
        #pragma unroll
        for (int i = 0; i < 4; i++)
            out[(cgn * 16 + quad * 4 + i) * HS_ + mh * 32 + ck * 16 + r16] =
                f2b(st[i]);
    }
#undef KSTG
}

// ---------------- K4: y = r @ state (MFMA), fused GroupNorm ----------------
__global__ __launch_bounds__(256) void rstate_gn_kernel(
    const u16* __restrict__ r, const u16* __restrict__ stT,
    const float* __restrict__ gnw, const float* __restrict__ gnb, u16* __restrict__ ygn)
{
    int blk = blockIdx.x;      // bh*NC + c
    int c  = blk & (NC_ - 1);
    int bh = blk >> 3;
    int h = bh & (H_ - 1);
    int b = bh >> 4;
    __shared__ __align__(16) u16 sT[HS_ * 72];   // pitch 72 u16
    int tid = threadIdx.x, lane = tid & 63, wave = tid >> 6;
    int r16 = lane & 15, quad = lane >> 4;

    const u16* sg = stT + (size_t)blk * (HS_ * HS_);
    for (int i = tid; i < 512; i += 256) {
        int n = i >> 3, c8 = (i & 7) * 8;
        *reinterpret_cast<u32x4*>(&sT[n * 72 + c8]) =
            *reinterpret_cast<const u32x4*>(sg + n * HS_ + c8);
    }
    __syncthreads();

    size_t rowBase = (size_t)(b * T_ + c * CHUNK_ + wave * 64);
    f32x4 acc[4][4];
    #pragma unroll
    for (int mi = 0; mi < 4; mi++)
        #pragma unroll
        for (int ni = 0; ni < 4; ni++)
            acc[mi][ni] = f32x4{0.f, 0.f, 0.f, 0.f};

    #pragma unroll
    for (int ks = 0; ks < 2; ks++) {
        int kb = ks * 32 + quad * 8;
        s16x8 fa[4], fb[4];
        #pragma unroll
        for (int mi = 0; mi < 4; mi++)
            fa[mi] = *reinterpret_cast<const s16x8*>(
                r + (rowBase + mi * 16 + r16) * C_ + h * HS_ + kb);
        #pragma unroll
        for (int ni = 0; ni < 4; ni++)
            fb[ni] = *reinterpret_cast<const s16x8*>(&sT[(ni * 16 + r16) * 72 + kb]);
        #pragma unroll
        for (int mi = 0; mi < 4; mi++)
            #pragma unroll
            for (int ni = 0; ni < 4; ni++)
                acc[mi][ni] = __builtin_amdgcn_mfma_f32_16x16x32_bf16(fa[mi], fb[ni], acc[mi][ni], 0, 0, 0);
    }

    float gwv[4], gbv[4];
    #pragma unroll
    for (int ni = 0; ni < 4; ni++) {
        int col = ni * 16 + r16;
        gwv[ni] = gnw[h * HS_ + col];
        gbv[ni] = gnb[h * HS_ + col];
    }
    #pragma unroll
    for (int mi = 0; mi < 4; mi++) {
        float s1[4], s2[4];
        #pragma unroll
        for (int i = 0; i < 4; i++) {
            float s = 0.f, ss = 0.f;
            #pragma unroll
            for (int ni = 0; ni < 4; ni++) {
                float v = acc[mi][ni][i];
                s += v; ss += v * v;
            }
            s1[i] = s; s2[i] = ss;
        }
        #pragma unroll
        for (int d = 1; d < 16; d <<= 1) {
            #pragma unroll
            for (int i = 0; i < 4; i++) {
                s1[i] += __shfl_xor(s1[i], d);
                s2[i] += __shfl_xor(s2[i], d);
            }
        }
        #pragma unroll
        for (int i = 0; i < 4; i++) {
            float mu = s1[i] * (1.f / 64.f);
            float var = s2[i] * (1.f / 64.f) - mu * mu;
            float sc = rsqrtf(var + 1e-5f);
            size_t ob = (rowBase + mi * 16 + quad * 4 + i) * C_ + h * HS_;
            #pragma unroll
            for (int ni = 0; ni < 4; ni++)
                ygn[ob + ni * 16 + r16] = f2b((acc[mi][ni][i] - mu) * sc * gwv[ni] + gbv[ni]);
        }
    }
}

// ---------------------------------------------------------------------------
extern "C" void kernel_launch(void* const* d_in, const int* in_sizes, int n_in,
                              void* d_out, int out_size, void* d_ws, size_t ws_size,
                              hipStream_t stream) {
    const float* x    = (const float*)d_in[0];
    const float* vol  = (const float*)d_in[1];
    const float* Wvol = (const float*)d_in[2];
    const float* bvol = (const float*)d_in[3];
    const float* mk   = (const float*)d_in[4];
    const float* mv   = (const float*)d_in[5];
    const float* mr   = (const float*)d_in[6];
    const float* td   = (const float*)d_in[7];
    const float* Wk   = (const float*)d_in[8];
    const float* Wv   = (const float*)d_in[9];
    const float* Wr   = (const float*)d_in[10];
    const float* Wo   = (const float*)d_in[11];
    const float* gnw  = (const float*)d_in[12];
    const float* gnb  = (const float*)d_in[13];
    float* out = (float*)d_out;

    // one-time: allow big dynamic LDS (host-side, capture-safe)
    static bool init_attr = []() {
        hipFuncSetAttribute(reinterpret_cast<const void*>(gemm_bt<0>),
                            hipFuncAttributeMaxDynamicSharedMemorySize, GEMM_LDS_BYTES);
        hipFuncSetAttribute(reinterpret_cast<const void*>(gemm_bt<1>),
                            hipFuncAttributeMaxDynamicSharedMemorySize, GEMM_LDS_BYTES);
        hipFuncSetAttribute(reinterpret_cast<const void*>(gemm_bt<2>),
                            hipFuncAttributeMaxDynamicSharedMemorySize, GEMM_LDS_BYTES);
        hipFuncSetAttribute(reinterpret_cast<const void*>(kvscan_kernel),
                            hipFuncAttributeMaxDynamicSharedMemorySize, KVS_LDS_BYTES);
        return true;
    }();
    (void)init_attr;

    char* ws = (char*)d_ws;
    const size_t SLOT = (size_t)B_ * T_ * C_ * 2;   // 33,554,432 B
    // s0: xr -> kbT -> ygn ; s1: xk -> vbT ; s2: xv -> stT ; s3: rb
    u16* xr = (u16*)(ws + 0 * SLOT);
    u16* xk = (u16*)(ws + 1 * SLOT);
    u16* xv = (u16*)(ws + 2 * SLOT);
    u16* rb = (u16*)(ws + 3 * SLOT);
    u16* kbT = (u16*)(ws + 0 * SLOT);                    // PKT packed
    u16* vbT = (u16*)(ws + 1 * SLOT);                    // PKT packed
    u16* stT = (u16*)(ws + 2 * SLOT + SLOT / 2);         // 8.4 MB
    u16* ygn = (u16*)(ws + 0 * SLOT);
    u16* wtb = (u16*)(ws + 4 * SLOT);                    // 4 bf16 weight mats
    u16* wrb = wtb;
    u16* wkb = wrb + (size_t)C_ * C_;
    u16* wvb = wkb + (size_t)C_ * C_;
    u16* wob = wvb + (size_t)C_ * C_;

    cvt4_kernel<<<dim3(4 * (C_ * C_ / 8) / 256), dim3(256), 0, stream>>>(Wr, Wk, Wv, Wo, wtb);

    // B*(T/4)*(C/8) threads = 524288 -> 2048 blocks
    mix_kernel<<<dim3(2048), dim3(256), 0, stream>>>(
        x, vol, Wvol, bvol, mk, mv, mr, xk, xv, xr);

    // 64 bm-tiles x 4 bn-tiles; id = bn*64+bm so A-panel sharers co-XCD
    gemm_bt<1><<<dim3(256), dim3(512), GEMM_LDS_BYTES, stream>>>(xr, wrb, rb);
    gemm_bt<2><<<dim3(256), dim3(512), GEMM_LDS_BYTES, stream>>>(xk, wkb, kbT);
    gemm_bt<2><<<dim3(256), dim3(512), GEMM_LDS_BYTES, stream>>>(xv, wvb, vbT);

    // fused kv-outer + decay scan: 256 blocks (b,h,m-half), 512 threads
    kvscan_kernel<<<dim3(B_ * H_ * 2), dim3(512), KVS_LDS_BYTES, stream>>>(kbT, vbT, td, stT);

    rstate_gn_kernel<<<dim3(B_ * H_ * NC_), dim3(256), 0, stream>>>(rb, stT, gnw, gnb, ygn);

    gemm_bt<0><<<dim3(256), dim3(512), GEMM_LDS_BYTES, stream>>>(ygn, wob, out);
}

// Round 7
// 329.538 us; speedup vs baseline: 1.0498x; 1.0498x over previous
//
#include <hip/hip_runtime.h>

typedef unsigned short u16;
typedef __attribute__((ext_vector_type(4))) unsigned int u32x4;
typedef __attribute__((ext_vector_type(4))) float f32x4;
typedef __attribute__((ext_vector_type(8))) short s16x8;

#define B_ 8
#define T_ 2048
#define C_ 1024
#define H_ 16
#define HS_ 64
#define CHUNK_ 256
#define NC_ 8

union U8 { u32x4 u; u16 h[8]; };

__device__ __forceinline__ float b2f(u16 v) {
    union { unsigned int i; float f; } c; c.i = ((unsigned int)v) << 16; return c.f;
}
__device__ __forceinline__ u16 f2b(float f) {
    union { float f; unsigned int i; } c; c.f = f;
    unsigned int i = c.i;
    return (u16)((i + 0x7FFFu + ((i >> 16) & 1u)) >> 16);  // RNE
}
// fast sigmoid: v_exp_f32 + v_rcp_f32 (args here are tiny, ~0.02 — no range issues)
__device__ __forceinline__ float fsig(float z) {
    return __builtin_amdgcn_rcpf(1.f + __expf(-z));
}

// async 16B global->LDS (lds dest = wave-uniform base + lane*16)
typedef __attribute__((address_space(1))) void GV;
typedef __attribute__((address_space(3))) void LV;
__device__ __forceinline__ void glds16(const void* g, void* l) {
    __builtin_amdgcn_global_load_lds((GV*)g, (LV*)l, 16, 0, 0);
}

// ---------------- K0: f32 -> bf16 conversion of the 4 weight matrices ------
__global__ __launch_bounds__(256) void cvt4_kernel(
    const float* __restrict__ s0, const float* __restrict__ s1,
    const float* __restrict__ s2, const float* __restrict__ s3,
    u16* __restrict__ dst)
{
    int i = blockIdx.x * 256 + threadIdx.x;   // 4 * 131072 threads, 8 elems each
    int m = i >> 17;
    const float* s = (m == 0) ? s0 : (m == 1) ? s1 : (m == 2) ? s2 : s3;
    size_t j = (size_t)(i & 131071) * 8;
    f32x4 a = *reinterpret_cast<const f32x4*>(s + j);
    f32x4 b = *reinterpret_cast<const f32x4*>(s + j + 4);
    U8 o;
    #pragma unroll
    for (int k = 0; k < 4; k++) { o.h[k] = f2b(a[k]); o.h[4 + k] = f2b(b[k]); }
    *reinterpret_cast<u32x4*>(dst + (size_t)m * C_ * C_ + j) = o.u;
}

// ---------------- K1: gate + time-shift + maa mix, 4-row t-strip ------------
__global__ __launch_bounds__(256) void mix_kernel(
    const float* __restrict__ x, const float* __restrict__ vol,
    const float* __restrict__ Wvol, const float* __restrict__ bvol,
    const float* __restrict__ mk, const float* __restrict__ mv, const float* __restrict__ mr,
    u16* __restrict__ xk, u16* __restrict__ xv, u16* __restrict__ xr)
{
    int idx = blockIdx.x * 256 + threadIdx.x;      // B*(T/4)*(C/8) threads
    int c0 = (idx & 127) * 8;
    int bt4 = idx >> 7;
    int t0  = (bt4 & 511) * 4;
    int b   = bt4 >> 9;
    size_t rowOff = ((size_t)b * T_ + t0) * C_ + c0;

    float wv[8], bv[8], mkv[8], mvv[8], mrv[8];
    #pragma unroll
    for (int j = 0; j < 8; j += 4) {
        f32x4 a;
        a = *reinterpret_cast<const f32x4*>(Wvol + c0 + j);
        wv[j] = a[0]; wv[j+1] = a[1]; wv[j+2] = a[2]; wv[j+3] = a[3];
        a = *reinterpret_cast<const f32x4*>(bvol + c0 + j);
        bv[j] = a[0]; bv[j+1] = a[1]; bv[j+2] = a[2]; bv[j+3] = a[3];
        a = *reinterpret_cast<const f32x4*>(mk + c0 + j);
        mkv[j] = a[0]; mkv[j+1] = a[1]; mkv[j+2] = a[2]; mkv[j+3] = a[3];
        a = *reinterpret_cast<const f32x4*>(mv + c0 + j);
        mvv[j] = a[0]; mvv[j+1] = a[1]; mvv[j+2] = a[2]; mvv[j+3] = a[3];
        a = *reinterpret_cast<const f32x4*>(mr + c0 + j);
        mrv[j] = a[0]; mrv[j+1] = a[1]; mrv[j+2] = a[2]; mrv[j+3] = a[3];
    }

    const float* volb = vol + (size_t)b * T_;
    float gp[8];
    if (t0 == 0) {
        #pragma unroll
        for (int j = 0; j < 8; j++) gp[j] = 0.f;
    } else {
        float vp = volb[t0 - 1];
        #pragma unroll
        for (int j = 0; j < 8; j += 4) {
            f32x4 a = *reinterpret_cast<const f32x4*>(x + rowOff - C_ + j);
            gp[j]   = a[0] * fsig(vp * wv[j]   + bv[j]);
            gp[j+1] = a[1] * fsig(vp * wv[j+1] + bv[j+1]);
            gp[j+2] = a[2] * fsig(vp * wv[j+2] + bv[j+2]);
            gp[j+3] = a[3] * fsig(vp * wv[j+3] + bv[j+3]);
        }
    }

    #pragma unroll
    for (int s = 0; s < 4; s++) {
        float vc = volb[t0 + s];
        size_t off = rowOff + (size_t)s * C_;
        float g[8];
        #pragma unroll
        for (int j = 0; j < 8; j += 4) {
            f32x4 a = *reinterpret_cast<const f32x4*>(x + off + j);
            g[j]   = a[0] * fsig(vc * wv[j]   + bv[j]);
            g[j+1] = a[1] * fsig(vc * wv[j+1] + bv[j+1]);
            g[j+2] = a[2] * fsig(vc * wv[j+2] + bv[j+2]);
            g[j+3] = a[3] * fsig(vc * wv[j+3] + bv[j+3]);
        }
        U8 ok, ov, orr;
        #pragma unroll
        for (int j = 0; j < 8; j++) {
            float xx = gp[j] - g[j];
            ok.h[j]  = f2b(g[j] + xx * mkv[j]);
            ov.h[j]  = f2b(g[j] + xx * mvv[j]);
            orr.h[j] = f2b(g[j] + xx * mrv[j]);
            gp[j] = g[j];
        }
        *reinterpret_cast<u32x4*>(xk + off) = ok.u;
        *reinterpret_cast<u32x4*>(xv + off) = ov.u;
        *reinterpret_cast<u32x4*>(xr + off) = orr.u;
    }
}

// ---------------- K2: C = A @ W^T  (4-phase, counted-vmcnt pipeline) --------
// 256x256 tile, BK=64, 8 waves (2M x 4N), 512 threads, LDS 128 KB double-buf.
// Tile t+1 staged in CONSUMPTION-ORDERED full-row quanta:
//   QA  (A all 256 rows, 4 glds/wave)   issued at ph0 of tile t
//   QB0 (B rows bit5==0, 2 glds/wave)   issued at ph1
//   QB1 (B rows bit5==1, 2 glds/wave)   issued at ph2
// Waits (own-wave, pre-barrier): ph0 vmcnt(2) [QB1(t) stays in flight],
// ph1 vmcnt(4) [QA(t+1) stays in flight]. Queue never drains in steady
// state; each wait has ~3 phases of slack. 4 barriers/K-tile.
// Race audit (r6): buffer slot t&1 overwritten by SQA(t+2) only after
// ph0(t+1)'s barrier; every wave drained its ph3 ds_reads via lgkmcnt(0)
// before that barrier -> no read/write overlap. All waves uniform barriers.
#define GBM_ 256
#define GBN_ 256
#define GBK_ 64
#define GK_  1024
#define GNT_ 16                    // GK_/GBK_
#define GEMM_LDS_BYTES 131072      // 2 * (256*64 + 256*64) * 2B

template<int MODE>
__global__ __launch_bounds__(512, 2) void gemm_bt(
    const u16* __restrict__ A, const u16* __restrict__ W, void* __restrict__ Cc)
{
    extern __shared__ __align__(16) u16 lds[];
    const int tid  = threadIdx.x;
    const int lane = tid & 63, w = tid >> 6;
    const int r16  = lane & 15, quad = lane >> 4;
    const int wm2  = w >> 2;         // 0..1 : M-half (128 rows)
    const int wn4  = w & 3;          // 0..3 : N-quarter (64 cols)
    const int id   = blockIdx.x;
    const int bm   = id & 63, bn = id >> 6;

    const u16* Ab = A + (size_t)bm * GBM_ * GK_;
    const u16* Wb = W + (size_t)bn * GBN_ * GK_;

    // per-lane staging source (pre-swizzled): lane -> row_in_8 = lane>>3,
    // global chunk = (lane&7)^(lane>>3); every glds16 covers 8 full rows.
    const int srow8  = lane >> 3;
    const int schunk = ((lane & 7) ^ srow8) * 8;            // elems
    const u16* aSrc  = Ab + (size_t)(w * 16 + srow8) * GK_ + schunk;
    const u16* bSrcR = Wb + (size_t)srow8 * GK_ + schunk;   // + row*GK_ later

    // fragment read bases (u16 elems). LDS row pitch = 64 elems (128 B).
    const int fA0 = (wm2 * 128 + r16) * 64;
    const int fB0 = 16384 + (wn4 * 64 + r16) * 64;
    const int c0 = ((quad)     ^ (r16 & 7)) * 8;            // ks=0 chunk ofs
    const int c1 = ((quad | 4) ^ (r16 & 7)) * 8;            // ks=1 chunk ofs

    // B-quantum row bases for this wave (8-row blocks within bit5 groups)
    const int i0_ = w * 2, i1_ = w * 2 + 1;
    const int rB0 = (i0_ >> 2) * 64 + (i0_ & 3) * 8;        // QB0 block 0
    const int rB1 = (i1_ >> 2) * 64 + (i1_ & 3) * 8;        // QB0 block 1

    f32x4 acc[8][4];
    #pragma unroll
    for (int mi = 0; mi < 8; mi++)
        #pragma unroll
        for (int ni = 0; ni < 4; ni++)
            acc[mi][ni] = f32x4{0.f, 0.f, 0.f, 0.f};

#define SQA(tt) do {                                                          \
    const size_t ko_ = (size_t)(tt) * 64;                                     \
    u16* db_ = lds + (((tt) & 1) * 32768) + w * 1024;                         \
    glds16(aSrc + ko_,                 db_);                                  \
    glds16(aSrc + 8   * GK_ + ko_,     db_ + 512);                            \
    glds16(aSrc + 128 * GK_ + ko_,     db_ + 8192);                           \
    glds16(aSrc + 136 * GK_ + ko_,     db_ + 8192 + 512);                     \
} while (0)

#define SQB(tt, hi) do {                                                      \
    const size_t ko_ = (size_t)(tt) * 64;                                     \
    u16* bb_ = lds + (((tt) & 1) * 32768) + 16384;                            \
    const int ra_ = rB0 + (hi) * 32, rb_ = rB1 + (hi) * 32;                   \
    glds16(bSrcR + (size_t)ra_ * GK_ + ko_, bb_ + ra_ * 64);                  \
    glds16(bSrcR + (size_t)rb_ * GK_ + ko_, bb_ + rb_ * 64);                  \
} while (0)

#define PH_BAR() do { asm volatile("" ::: "memory");                          \
    __builtin_amdgcn_s_barrier(); asm volatile("" ::: "memory"); } while (0)
#define PH_LGKM0() do { asm volatile("s_waitcnt lgkmcnt(0)" ::: "memory");    \
    __builtin_amdgcn_sched_barrier(0); } while (0)
#define LDFA(CO) { _Pragma("unroll") for (int mi = 0; mi < 8; mi++)           \
    fa[mi] = *reinterpret_cast<const s16x8*>(lds + pb + fA0 + mi * 1024 + (CO)); }
#define LDFB(NH, CO) { _Pragma("unroll") for (int ni = 0; ni < 2; ni++)       \
    fb[ni] = *reinterpret_cast<const s16x8*>(lds + pb + fB0 + ((NH) * 2 + ni) * 1024 + (CO)); }
#define MFMA16(NH) do { __builtin_amdgcn_s_setprio(1);                        \
    _Pragma("unroll") for (int mi = 0; mi < 8; mi++) {                        \
        acc[mi][(NH)*2+0] = __builtin_amdgcn_mfma_f32_16x16x32_bf16(          \
            fa[mi], fb[0], acc[mi][(NH)*2+0], 0, 0, 0);                       \
        acc[mi][(NH)*2+1] = __builtin_amdgcn_mfma_f32_16x16x32_bf16(          \
            fa[mi], fb[1], acc[mi][(NH)*2+1], 0, 0, 0);                       \
    } __builtin_amdgcn_s_setprio(0); } while (0)

    // prologue: stage tile 0 in quantum order (FIFO: QA, QB0, QB1)
    SQA(0); SQB(0, 0); SQB(0, 1);

    for (int t = 0; t < GNT_; ++t) {
        const int pb = (t & 1) * 32768;
        s16x8 fa[8], fb[2];
        // ---- ph0 (ks0, nh0): needs QA(t)+QB0(t); QB1(t) may stay in flight
        asm volatile("s_waitcnt vmcnt(2)" ::: "memory");
        PH_BAR();
        LDFA(c0); LDFB(0, c0);
        if (t + 1 < GNT_) SQA(t + 1);
        PH_LGKM0(); MFMA16(0);
        // ---- ph1 (ks0, nh1): needs QB1(t); QA(t+1) may stay in flight
        if (t + 1 < GNT_) asm volatile("s_waitcnt vmcnt(4)" ::: "memory");
        else              asm volatile("s_waitcnt vmcnt(0)" ::: "memory");
        PH_BAR();
        LDFB(1, c0);
        if (t + 1 < GNT_) SQB(t + 1, 0);
        PH_LGKM0(); MFMA16(1);
        // ---- ph2 (ks1, nh0): all data landed; reads pre-barrier overlap
        LDFA(c1); LDFB(0, c1);
        PH_BAR();
        if (t + 1 < GNT_) SQB(t + 1, 1);
        PH_LGKM0(); MFMA16(0);
        // ---- ph3 (ks1, nh1)
        LDFB(1, c1);
        PH_BAR();
        PH_LGKM0(); MFMA16(1);
    }
#undef SQA
#undef SQB
#undef LDFA
#undef LDFB
#undef MFMA16
#undef PH_LGKM0
#undef PH_BAR

    // drain any tail staging and protect LDS reuse by the epilogue
    asm volatile("s_waitcnt vmcnt(0)" ::: "memory");
    __builtin_amdgcn_s_barrier();
    asm volatile("" ::: "memory");

    if constexpr (MODE == 0) {
        // f32: 16 lanes * 4B = 64B full lines — direct store
        float* C = (float*)Cc;
        #pragma unroll
        for (int mi = 0; mi < 8; mi++) {
            int row0 = bm * GBM_ + wm2 * 128 + mi * 16 + quad * 4;
            #pragma unroll
            for (int ni = 0; ni < 4; ni++) {
                int col = bn * GBN_ + wn4 * 64 + ni * 16 + r16;
                #pragma unroll
                for (int i = 0; i < 4; i++)
                    C[(size_t)(row0 + i) * C_ + col] = acc[mi][ni][i];
            }
        }
    } else if constexpr (MODE == 1) {
        // bf16 row-major: per-wave LDS patch [64][72] -> 128B-row dwordx4 stores
        u16* ep = lds + w * 4608;
        u16* C = (u16*)Cc;
        #pragma unroll
        for (int half = 0; half < 2; half++) {
            #pragma unroll
            for (int mi2 = 0; mi2 < 4; mi2++) {
                int mi = half * 4 + mi2;
                #pragma unroll
                for (int ni = 0; ni < 4; ni++)
                    #pragma unroll
                    for (int i = 0; i < 4; i++)
                        ep[(mi2 * 16 + quad * 4 + i) * 72 + ni * 16 + r16] =
                            f2b(acc[mi][ni][i]);
            }
            asm volatile("s_waitcnt lgkmcnt(0)" ::: "memory");
            __builtin_amdgcn_sched_barrier(0);
            #pragma unroll
            for (int it = 0; it < 8; it++) {
                int rr = it * 8 + (lane >> 3);
                u32x4 val = *reinterpret_cast<const u32x4*>(ep + rr * 72 + (lane & 7) * 8);
                size_t grow = (size_t)(bm * GBM_ + wm2 * 128 + half * 64 + rr);
                *reinterpret_cast<u32x4*>(
                    C + grow * C_ + bn * GBN_ + wn4 * 64 + (lane & 7) * 8) = val;
            }
            asm volatile("s_waitcnt vmcnt(0) lgkmcnt(0)" ::: "memory");
        }
    } else {
        // MODE 2: bf16 PKT. Per-wave LDS patch [64 cols][16 chunks of 8 rows],
        // chunk XOR-swizzled by col. Each store instr writes one FULL 1 KB
        // packed tile (64 lanes x 16B contiguous).
        u16* ep = lds + w * 8192;
        #pragma unroll
        for (int mi = 0; mi < 8; mi++) {
            const int chunk = mi * 2 + (quad >> 1);
            const int rsub = (quad & 1) * 4;
            #pragma unroll
            for (int ni = 0; ni < 4; ni++) {
                const int col = ni * 16 + r16;
                u16* p = ep + col * 128 + ((chunk ^ col) & 15) * 8 + rsub;
                p[0] = f2b(acc[mi][ni][0]);
                p[1] = f2b(acc[mi][ni][1]);
                p[2] = f2b(acc[mi][ni][2]);
                p[3] = f2b(acc[mi][ni][3]);
            }
        }
        asm volatile("s_waitcnt lgkmcnt(0)" ::: "memory");
        __builtin_amdgcn_sched_barrier(0);
        u16* C = (u16*)Cc;
        const int cl = lane >> 2, ch4 = lane & 3;
        const int gc0 = bn * 16 + wn4 * 4;       // c-group base (c>>4)
        const int tt0 = bm * 8 + wm2 * 4;        // t-tile base (t>>5)
        #pragma unroll
        for (int it = 0; it < 16; it++) {
            const int col_l = (it & 3) * 16 + cl;
            const int chunk = (it >> 2) * 4 + ch4;
            u32x4 val = *reinterpret_cast<const u32x4*>(
                ep + col_l * 128 + ((chunk ^ col_l) & 15) * 8);
            const size_t tile = (size_t)(gc0 + (it & 3)) * 512 + tt0 + (it >> 2);
            *reinterpret_cast<u32x4*>(C + tile * 512 + cl * 32 + ch4 * 8) = val;
        }
    }
}

// ---------------- K3: fused P = v^T k + decay scan (LDS-staged v2) ----------
#define KVS_LDS_BYTES 98304

__global__ __launch_bounds__(512) void kvscan_kernel(
    const u16* __restrict__ kT, const u16* __restrict__ vT,
    const float* __restrict__ td, u16* __restrict__ stT)
{
    extern __shared__ __align__(16) u16 klds[];
    const int bm2 = blockIdx.x;            // bh*2 + mh
    const int mh = bm2 & 1, bh = bm2 >> 1;
    const int h = bh & (H_ - 1), b = bh >> 4;
    const float wdec = expf(-expf(td[h]));
    const int tid = threadIdx.x, lane = tid & 63, w = tid >> 6;
    const int r16 = lane & 15, quad = lane >> 4;
    const int cgn = w >> 1;                // n-group 0..3 (16 rows)
    const int ck  = w & 1;                 // m-sub 0..1 (16 cols)
    const int tt0 = b * 64;                // t-tile base for this batch
    const int loff = r16 * 32 + quad * 8;  // lane offset within a 1KB tile

    // stage: 48 tiles (tau<32: v cgroup tau>>3, ks tau&7; else k)
#define KSTG(jj, bb) do {                                                     \
    u16* db_ = klds + (bb) * 24576;                                           \
    _Pragma("unroll")                                                         \
    for (int q = 0; q < 6; q++) {                                             \
        const int tau = w * 6 + q;                                            \
        const u16* src;                                                       \
        if (tau < 32)                                                         \
            src = vT + ((size_t)(h * 4 + (tau >> 3)) * 512 +                  \
                        tt0 + (jj) * 8 + (tau & 7)) * 512;                    \
        else                                                                  \
            src = kT + ((size_t)(h * 4 + mh * 2 + ((tau - 32) >> 3)) * 512 +  \
                        tt0 + (jj) * 8 + ((tau - 32) & 7)) * 512;             \
        glds16(src + (size_t)lane * 8, db_ + tau * 512);                      \
    }                                                                         \
} while (0)

    KSTG(0, 0);

    f32x4 st = f32x4{0.f, 0.f, 0.f, 0.f};
    for (int j = 0; j < NC_; ++j) {
        asm volatile("s_waitcnt vmcnt(0)" ::: "memory");
        __syncthreads();
        if (j + 1 < NC_) KSTG(j + 1, (j + 1) & 1);
        const u16* bb = klds + (j & 1) * 24576;
        f32x4 acc = f32x4{0.f, 0.f, 0.f, 0.f};
        #pragma unroll
        for (int ks = 0; ks < 8; ks++) {
            s16x8 fa = *reinterpret_cast<const s16x8*>(
                bb + (cgn * 8 + ks) * 512 + loff);
            s16x8 fb = *reinterpret_cast<const s16x8*>(
                bb + (32 + ck * 8 + ks) * 512 + loff);
            acc = __builtin_amdgcn_mfma_f32_16x16x32_bf16(fa, fb, acc, 0, 0, 0);
        }
        st = (st + acc) * wdec;
        u16* out = stT + ((size_t)bh * NC_ + j) * 4096;
        #pragma unroll
        for (int i = 0; i < 4; i++)
            out[(cgn * 16 + quad * 4 + i) * HS_ + mh * 32 + ck * 16 + r16] =
                f2b(st[i]);
    }
#undef KSTG
}

// ---------------- K4: y = r @ state (MFMA), fused GroupNorm ----------------
__global__ __launch_bounds__(256) void rstate_gn_kernel(
    const u16* __restrict__ r, const u16* __restrict__ stT,
    const float* __restrict__ gnw, const float* __restrict__ gnb, u16* __restrict__ ygn)
{
    int blk = blockIdx.x;      // bh*NC + c
    int c  = blk & (NC_ - 1);
    int bh = blk >> 3;
    int h = bh & (H_ - 1);
    int b = bh >> 4;
    __shared__ __align__(16) u16 sT[HS_ * 72];   // pitch 72 u16
    int tid = threadIdx.x, lane = tid & 63, wave = tid >> 6;
    int r16 = lane & 15, quad = lane >> 4;

    const u16* sg = stT + (size_t)blk * (HS_ * HS_);
    for (int i = tid; i < 512; i += 256) {
        int n = i >> 3, c8 = (i & 7) * 8;
        *reinterpret_cast<u32x4*>(&sT[n * 72 + c8]) =
            *reinterpret_cast<const u32x4*>(sg + n * HS_ + c8);
    }
    __syncthreads();

    size_t rowBase = (size_t)(b * T_ + c * CHUNK_ + wave * 64);
    f32x4 acc[4][4];
    #pragma unroll
    for (int mi = 0; mi < 4; mi++)
        #pragma unroll
        for (int ni = 0; ni < 4; ni++)
            acc[mi][ni] = f32x4{0.f, 0.f, 0.f, 0.f};

    #pragma unroll
    for (int ks = 0; ks < 2; ks++) {
        int kb = ks * 32 + quad * 8;
        s16x8 fa[4], fb[4];
        #pragma unroll
        for (int mi = 0; mi < 4; mi++)
            fa[mi] = *reinterpret_cast<const s16x8*>(
                r + (rowBase + mi * 16 + r16) * C_ + h * HS_ + kb);
        #pragma unroll
        for (int ni = 0; ni < 4; ni++)
            fb[ni] = *reinterpret_cast<const s16x8*>(&sT[(ni * 16 + r16) * 72 + kb]);
        #pragma unroll
        for (int mi = 0; mi < 4; mi++)
            #pragma unroll
            for (int ni = 0; ni < 4; ni++)
                acc[mi][ni] = __builtin_amdgcn_mfma_f32_16x16x32_bf16(fa[mi], fb[ni], acc[mi][ni], 0, 0, 0);
    }

    float gwv[4], gbv[4];
    #pragma unroll
    for (int ni = 0; ni < 4; ni++) {
        int col = ni * 16 + r16;
        gwv[ni] = gnw[h * HS_ + col];
        gbv[ni] = gnb[h * HS_ + col];
    }
    #pragma unroll
    for (int mi = 0; mi < 4; mi++) {
        float s1[4], s2[4];
        #pragma unroll
        for (int i = 0; i < 4; i++) {
            float s = 0.f, ss = 0.f;
            #pragma unroll
            for (int ni = 0; ni < 4; ni++) {
                float v = acc[mi][ni][i];
                s += v; ss += v * v;
            }
            s1[i] = s; s2[i] = ss;
        }
        #pragma unroll
        for (int d = 1; d < 16; d <<= 1) {
            #pragma unroll
            for (int i = 0; i < 4; i++) {
                s1[i] += __shfl_xor(s1[i], d);
                s2[i] += __shfl_xor(s2[i], d);
            }
        }
        #pragma unroll
        for (int i = 0; i < 4; i++) {
            float mu = s1[i] * (1.f / 64.f);
            float var = s2[i] * (1.f / 64.f) - mu * mu;
            float sc = rsqrtf(var + 1e-5f);
            size_t ob = (rowBase + mi * 16 + quad * 4 + i) * C_ + h * HS_;
            #pragma unroll
            for (int ni = 0; ni < 4; ni++)
                ygn[ob + ni * 16 + r16] = f2b((acc[mi][ni][i] - mu) * sc * gwv[ni] + gbv[ni]);
        }
    }
}

// ---------------------------------------------------------------------------
extern "C" void kernel_launch(void* const* d_in, const int* in_sizes, int n_in,
                              void* d_out, int out_size, void* d_ws, size_t ws_size,
                              hipStream_t stream) {
    const float* x    = (const float*)d_in[0];
    const float* vol  = (const float*)d_in[1];
    const float* Wvol = (const float*)d_in[2];
    const float* bvol = (const float*)d_in[3];
    const float* mk   = (const float*)d_in[4];
    const float* mv   = (const float*)d_in[5];
    const float* mr   = (const float*)d_in[6];
    const float* td   = (const float*)d_in[7];
    const float* Wk   = (const float*)d_in[8];
    const float* Wv   = (const float*)d_in[9];
    const float* Wr   = (const float*)d_in[10];
    const float* Wo   = (const float*)d_in[11];
    const float* gnw  = (const float*)d_in[12];
    const float* gnb  = (const float*)d_in[13];
    float* out = (float*)d_out;

    // one-time: allow big dynamic LDS (host-side, capture-safe)
    static bool init_attr = []() {
        hipFuncSetAttribute(reinterpret_cast<const void*>(gemm_bt<0>),
                            hipFuncAttributeMaxDynamicSharedMemorySize, GEMM_LDS_BYTES);
        hipFuncSetAttribute(reinterpret_cast<const void*>(gemm_bt<1>),
                            hipFuncAttributeMaxDynamicSharedMemorySize, GEMM_LDS_BYTES);
        hipFuncSetAttribute(reinterpret_cast<const void*>(gemm_bt<2>),
                            hipFuncAttributeMaxDynamicSharedMemorySize, GEMM_LDS_BYTES);
        hipFuncSetAttribute(reinterpret_cast<const void*>(kvscan_kernel),
                            hipFuncAttributeMaxDynamicSharedMemorySize, KVS_LDS_BYTES);
        return true;
    }();
    (void)init_attr;

    char* ws = (char*)d_ws;
    const size_t SLOT = (size_t)B_ * T_ * C_ * 2;   // 33,554,432 B
    // s0: xr -> kbT -> ygn ; s1: xk -> vbT ; s2: xv -> stT ; s3: rb
    u16* xr = (u16*)(ws + 0 * SLOT);
    u16* xk = (u16*)(ws + 1 * SLOT);
    u16* xv = (u16*)(ws + 2 * SLOT);
    u16* rb = (u16*)(ws + 3 * SLOT);
    u16* kbT = (u16*)(ws + 0 * SLOT);                    // PKT packed
    u16* vbT = (u16*)(ws + 1 * SLOT);                    // PKT packed
    u16* stT = (u16*)(ws + 2 * SLOT + SLOT / 2);         // 8.4 MB
    u16* ygn = (u16*)(ws + 0 * SLOT);
    u16* wtb = (u16*)(ws + 4 * SLOT);                    // 4 bf16 weight mats
    u16* wrb = wtb;
    u16* wkb = wrb + (size_t)C_ * C_;
    u16* wvb = wkb + (size_t)C_ * C_;
    u16* wob = wvb + (size_t)C_ * C_;

    cvt4_kernel<<<dim3(4 * (C_ * C_ / 8) / 256), dim3(256), 0, stream>>>(Wr, Wk, Wv, Wo, wtb);

    // B*(T/4)*(C/8) threads = 524288 -> 2048 blocks
    mix_kernel<<<dim3(2048), dim3(256), 0, stream>>>(
        x, vol, Wvol, bvol, mk, mv, mr, xk, xv, xr);

    // 64 bm-tiles x 4 bn-tiles; id = bn*64+bm so A-panel sharers co-XCD
    gemm_bt<1><<<dim3(256), dim3(512), GEMM_LDS_BYTES, stream>>>(xr, wrb, rb);
    gemm_bt<2><<<dim3(256), dim3(512), GEMM_LDS_BYTES, stream>>>(xk, wkb, kbT);
    gemm_bt<2><<<dim3(256), dim3(512), GEMM_LDS_BYTES, stream>>>(xv, wvb, vbT);

    // fused kv-outer + decay scan: 256 blocks (b,h,m-half), 512 threads
    kvscan_kernel<<<dim3(B_ * H_ * 2), dim3(512), KVS_LDS_BYTES, stream>>>(kbT, vbT, td, stT);

    rstate_gn_kernel<<<dim3(B_ * H_ * NC_), dim3(256), 0, stream>>>(rb, stT, gnw, gnb, ygn);

    gemm_bt<0><<<dim3(256), dim3(512), GEMM_LDS_BYTES, stream>>>(ygn, wob, out);
}

// Round 8
// 312.560 us; speedup vs baseline: 1.1069x; 1.0543x over previous
//
#include <hip/hip_runtime.h>

typedef unsigned short u16;
typedef __attribute__((ext_vector_type(4))) unsigned int u32x4;
typedef __attribute__((ext_vector_type(4))) float f32x4;
typedef __attribute__((ext_vector_type(8))) short s16x8;

#define B_ 8
#define T_ 2048
#define C_ 1024
#define H_ 16
#define HS_ 64
#define CHUNK_ 256
#define NC_ 8

union U8 { u32x4 u; u16 h[8]; };

__device__ __forceinline__ float b2f(u16 v) {
    union { unsigned int i; float f; } c; c.i = ((unsigned int)v) << 16; return c.f;
}
__device__ __forceinline__ u16 f2b(float f) {
    union { float f; unsigned int i; } c; c.f = f;
    unsigned int i = c.i;
    return (u16)((i + 0x7FFFu + ((i >> 16) & 1u)) >> 16);  // RNE
}
// fast sigmoid: v_exp_f32 + v_rcp_f32 (args here are tiny, ~0.02 — no range issues)
__device__ __forceinline__ float fsig(float z) {
    return __builtin_amdgcn_rcpf(1.f + __expf(-z));
}

// async 16B global->LDS (lds dest = wave-uniform base + lane*16)
typedef __attribute__((address_space(1))) void GV;
typedef __attribute__((address_space(3))) void LV;
__device__ __forceinline__ void glds16(const void* g, void* l) {
    __builtin_amdgcn_global_load_lds((GV*)g, (LV*)l, 16, 0, 0);
}

// ---------------- K1: prep = {gate+shift+maa mix} ∪ {weight f32->bf16} ------
// blocks [0,2048): mix (B*(T/4)*(C/8) threads, 4-row t-strip)
// blocks [2048,4096): cvt of the 4 weight matrices (524288 threads, 8 el ea)
// Two independent memory streams co-resident -> higher combined HBM util
// than running them back-to-back (mix alone plateaued at 41% peak).
__global__ __launch_bounds__(256) void prep_kernel(
    const float* __restrict__ x, const float* __restrict__ vol,
    const float* __restrict__ Wvol, const float* __restrict__ bvol,
    const float* __restrict__ mk, const float* __restrict__ mv, const float* __restrict__ mr,
    u16* __restrict__ xk, u16* __restrict__ xv, u16* __restrict__ xr,
    const float* __restrict__ s0, const float* __restrict__ s1,
    const float* __restrict__ s2, const float* __restrict__ s3,
    u16* __restrict__ wdst)
{
    if (blockIdx.x >= 2048) {
        // ---- cvt part ----
        int i = (blockIdx.x - 2048) * 256 + threadIdx.x;
        int m = i >> 17;
        const float* s = (m == 0) ? s0 : (m == 1) ? s1 : (m == 2) ? s2 : s3;
        size_t j = (size_t)(i & 131071) * 8;
        f32x4 a = *reinterpret_cast<const f32x4*>(s + j);
        f32x4 b = *reinterpret_cast<const f32x4*>(s + j + 4);
        U8 o;
        #pragma unroll
        for (int k = 0; k < 4; k++) { o.h[k] = f2b(a[k]); o.h[4 + k] = f2b(b[k]); }
        *reinterpret_cast<u32x4*>(wdst + (size_t)m * C_ * C_ + j) = o.u;
        return;
    }
    // ---- mix part ----
    int idx = blockIdx.x * 256 + threadIdx.x;      // B*(T/4)*(C/8) threads
    int c0 = (idx & 127) * 8;
    int bt4 = idx >> 7;
    int t0  = (bt4 & 511) * 4;
    int b   = bt4 >> 9;
    size_t rowOff = ((size_t)b * T_ + t0) * C_ + c0;

    float wv[8], bv[8], mkv[8], mvv[8], mrv[8];
    #pragma unroll
    for (int j = 0; j < 8; j += 4) {
        f32x4 a;
        a = *reinterpret_cast<const f32x4*>(Wvol + c0 + j);
        wv[j] = a[0]; wv[j+1] = a[1]; wv[j+2] = a[2]; wv[j+3] = a[3];
        a = *reinterpret_cast<const f32x4*>(bvol + c0 + j);
        bv[j] = a[0]; bv[j+1] = a[1]; bv[j+2] = a[2]; bv[j+3] = a[3];
        a = *reinterpret_cast<const f32x4*>(mk + c0 + j);
        mkv[j] = a[0]; mkv[j+1] = a[1]; mkv[j+2] = a[2]; mkv[j+3] = a[3];
        a = *reinterpret_cast<const f32x4*>(mv + c0 + j);
        mvv[j] = a[0]; mvv[j+1] = a[1]; mvv[j+2] = a[2]; mvv[j+3] = a[3];
        a = *reinterpret_cast<const f32x4*>(mr + c0 + j);
        mrv[j] = a[0]; mrv[j+1] = a[1]; mrv[j+2] = a[2]; mrv[j+3] = a[3];
    }

    const float* volb = vol + (size_t)b * T_;
    float gp[8];
    if (t0 == 0) {
        #pragma unroll
        for (int j = 0; j < 8; j++) gp[j] = 0.f;
    } else {
        float vp = volb[t0 - 1];
        #pragma unroll
        for (int j = 0; j < 8; j += 4) {
            f32x4 a = *reinterpret_cast<const f32x4*>(x + rowOff - C_ + j);
            gp[j]   = a[0] * fsig(vp * wv[j]   + bv[j]);
            gp[j+1] = a[1] * fsig(vp * wv[j+1] + bv[j+1]);
            gp[j+2] = a[2] * fsig(vp * wv[j+2] + bv[j+2]);
            gp[j+3] = a[3] * fsig(vp * wv[j+3] + bv[j+3]);
        }
    }

    #pragma unroll
    for (int s = 0; s < 4; s++) {
        float vc = volb[t0 + s];
        size_t off = rowOff + (size_t)s * C_;
        float g[8];
        #pragma unroll
        for (int j = 0; j < 8; j += 4) {
            f32x4 a = *reinterpret_cast<const f32x4*>(x + off + j);
            g[j]   = a[0] * fsig(vc * wv[j]   + bv[j]);
            g[j+1] = a[1] * fsig(vc * wv[j+1] + bv[j+1]);
            g[j+2] = a[2] * fsig(vc * wv[j+2] + bv[j+2]);
            g[j+3] = a[3] * fsig(vc * wv[j+3] + bv[j+3]);
        }
        U8 ok, ov, orr;
        #pragma unroll
        for (int j = 0; j < 8; j++) {
            float xx = gp[j] - g[j];
            ok.h[j]  = f2b(g[j] + xx * mkv[j]);
            ov.h[j]  = f2b(g[j] + xx * mvv[j]);
            orr.h[j] = f2b(g[j] + xx * mrv[j]);
            gp[j] = g[j];
        }
        *reinterpret_cast<u32x4*>(xk + off) = ok.u;
        *reinterpret_cast<u32x4*>(xv + off) = ov.u;
        *reinterpret_cast<u32x4*>(xr + off) = orr.u;
    }
}

// ---------------- K2 core: C = A @ W^T  (4-phase, counted-vmcnt pipeline) ---
// 256x256 tile, BK=64, 8 waves (2M x 4N), 512 threads, LDS 128 KB double-buf.
// Consumption-ordered staging quanta QA / QB0 / QB1 issued at ph0/ph1/ph2;
// waits vmcnt(2)/vmcnt(4) keep the VMEM queue non-empty in steady state.
// MODE 0: f32 row-major; MODE 1: bf16 row-major; MODE 2: bf16 PKT packed
// transposed (16c x 32t tiles of 1 KB).
#define GBM_ 256
#define GBN_ 256
#define GBK_ 64
#define GK_  1024
#define GNT_ 16                    // GK_/GBK_
#define GEMM_LDS_BYTES 131072      // 2 * (256*64 + 256*64) * 2B

template<int MODE>
__device__ __forceinline__ void gemm_core(
    u16* lds, const u16* __restrict__ A, const u16* __restrict__ W,
    void* __restrict__ Cc, const int id)
{
    const int tid  = threadIdx.x;
    const int lane = tid & 63, w = tid >> 6;
    const int r16  = lane & 15, quad = lane >> 4;
    const int wm2  = w >> 2;         // 0..1 : M-half (128 rows)
    const int wn4  = w & 3;          // 0..3 : N-quarter (64 cols)
    const int bm   = id & 63, bn = id >> 6;

    const u16* Ab = A + (size_t)bm * GBM_ * GK_;
    const u16* Wb = W + (size_t)bn * GBN_ * GK_;

    const int srow8  = lane >> 3;
    const int schunk = ((lane & 7) ^ srow8) * 8;            // elems
    const u16* aSrc  = Ab + (size_t)(w * 16 + srow8) * GK_ + schunk;
    const u16* bSrcR = Wb + (size_t)srow8 * GK_ + schunk;   // + row*GK_ later

    const int fA0 = (wm2 * 128 + r16) * 64;
    const int fB0 = 16384 + (wn4 * 64 + r16) * 64;
    const int c0 = ((quad)     ^ (r16 & 7)) * 8;            // ks=0 chunk ofs
    const int c1 = ((quad | 4) ^ (r16 & 7)) * 8;            // ks=1 chunk ofs

    const int i0_ = w * 2, i1_ = w * 2 + 1;
    const int rB0 = (i0_ >> 2) * 64 + (i0_ & 3) * 8;
    const int rB1 = (i1_ >> 2) * 64 + (i1_ & 3) * 8;

    f32x4 acc[8][4];
    #pragma unroll
    for (int mi = 0; mi < 8; mi++)
        #pragma unroll
        for (int ni = 0; ni < 4; ni++)
            acc[mi][ni] = f32x4{0.f, 0.f, 0.f, 0.f};

#define SQA(tt) do {                                                          \
    const size_t ko_ = (size_t)(tt) * 64;                                     \
    u16* db_ = lds + (((tt) & 1) * 32768) + w * 1024;                         \
    glds16(aSrc + ko_,                 db_);                                  \
    glds16(aSrc + 8   * GK_ + ko_,     db_ + 512);                            \
    glds16(aSrc + 128 * GK_ + ko_,     db_ + 8192);                           \
    glds16(aSrc + 136 * GK_ + ko_,     db_ + 8192 + 512);                     \
} while (0)

#define SQB(tt, hi) do {                                                      \
    const size_t ko_ = (size_t)(tt) * 64;                                     \
    u16* bb_ = lds + (((tt) & 1) * 32768) + 16384;                            \
    const int ra_ = rB0 + (hi) * 32, rb_ = rB1 + (hi) * 32;                   \
    glds16(bSrcR + (size_t)ra_ * GK_ + ko_, bb_ + ra_ * 64);                  \
    glds16(bSrcR + (size_t)rb_ * GK_ + ko_, bb_ + rb_ * 64);                  \
} while (0)

#define PH_BAR() do { asm volatile("" ::: "memory");                          \
    __builtin_amdgcn_s_barrier(); asm volatile("" ::: "memory"); } while (0)
#define PH_LGKM0() do { asm volatile("s_waitcnt lgkmcnt(0)" ::: "memory");    \
    __builtin_amdgcn_sched_barrier(0); } while (0)
#define LDFA(CO) { _Pragma("unroll") for (int mi = 0; mi < 8; mi++)           \
    fa[mi] = *reinterpret_cast<const s16x8*>(lds + pb + fA0 + mi * 1024 + (CO)); }
#define LDFB(NH, CO) { _Pragma("unroll") for (int ni = 0; ni < 2; ni++)       \
    fb[ni] = *reinterpret_cast<const s16x8*>(lds + pb + fB0 + ((NH) * 2 + ni) * 1024 + (CO)); }
#define MFMA16(NH) do { __builtin_amdgcn_s_setprio(1);                        \
    _Pragma("unroll") for (int mi = 0; mi < 8; mi++) {                        \
        acc[mi][(NH)*2+0] = __builtin_amdgcn_mfma_f32_16x16x32_bf16(          \
            fa[mi], fb[0], acc[mi][(NH)*2+0], 0, 0, 0);                       \
        acc[mi][(NH)*2+1] = __builtin_amdgcn_mfma_f32_16x16x32_bf16(          \
            fa[mi], fb[1], acc[mi][(NH)*2+1], 0, 0, 0);                       \
    } __builtin_amdgcn_s_setprio(0); } while (0)

    // prologue: stage tile 0 in quantum order (FIFO: QA, QB0, QB1)
    SQA(0); SQB(0, 0); SQB(0, 1);

    for (int t = 0; t < GNT_; ++t) {
        const int pb = (t & 1) * 32768;
        s16x8 fa[8], fb[2];
        // ---- ph0 (ks0, nh0): needs QA(t)+QB0(t); QB1(t) may stay in flight
        asm volatile("s_waitcnt vmcnt(2)" ::: "memory");
        PH_BAR();
        LDFA(c0); LDFB(0, c0);
        if (t + 1 < GNT_) SQA(t + 1);
        PH_LGKM0(); MFMA16(0);
        // ---- ph1 (ks0, nh1): needs QB1(t); QA(t+1) may stay in flight
        if (t + 1 < GNT_) asm volatile("s_waitcnt vmcnt(4)" ::: "memory");
        else              asm volatile("s_waitcnt vmcnt(0)" ::: "memory");
        PH_BAR();
        LDFB(1, c0);
        if (t + 1 < GNT_) SQB(t + 1, 0);
        PH_LGKM0(); MFMA16(1);
        // ---- ph2 (ks1, nh0): all data landed; reads pre-barrier overlap
        LDFA(c1); LDFB(0, c1);
        PH_BAR();
        if (t + 1 < GNT_) SQB(t + 1, 1);
        PH_LGKM0(); MFMA16(0);
        // ---- ph3 (ks1, nh1)
        LDFB(1, c1);
        PH_BAR();
        PH_LGKM0(); MFMA16(1);
    }
#undef SQA
#undef SQB
#undef LDFA
#undef LDFB
#undef MFMA16
#undef PH_LGKM0
#undef PH_BAR

    // drain any tail staging and protect LDS reuse by the epilogue
    asm volatile("s_waitcnt vmcnt(0)" ::: "memory");
    __builtin_amdgcn_s_barrier();
    asm volatile("" ::: "memory");

    if constexpr (MODE == 0) {
        // f32: 16 lanes * 4B = 64B full lines — direct store
        float* C = (float*)Cc;
        #pragma unroll
        for (int mi = 0; mi < 8; mi++) {
            int row0 = bm * GBM_ + wm2 * 128 + mi * 16 + quad * 4;
            #pragma unroll
            for (int ni = 0; ni < 4; ni++) {
                int col = bn * GBN_ + wn4 * 64 + ni * 16 + r16;
                #pragma unroll
                for (int i = 0; i < 4; i++)
                    C[(size_t)(row0 + i) * C_ + col] = acc[mi][ni][i];
            }
        }
    } else if constexpr (MODE == 1) {
        // bf16 row-major: per-wave LDS patch [64][72] -> 128B-row dwordx4 stores
        u16* ep = lds + w * 4608;
        u16* C = (u16*)Cc;
        #pragma unroll
        for (int half = 0; half < 2; half++) {
            #pragma unroll
            for (int mi2 = 0; mi2 < 4; mi2++) {
                int mi = half * 4 + mi2;
                #pragma unroll
                for (int ni = 0; ni < 4; ni++)
                    #pragma unroll
                    for (int i = 0; i < 4; i++)
                        ep[(mi2 * 16 + quad * 4 + i) * 72 + ni * 16 + r16] =
                            f2b(acc[mi][ni][i]);
            }
            asm volatile("s_waitcnt lgkmcnt(0)" ::: "memory");
            __builtin_amdgcn_sched_barrier(0);
            #pragma unroll
            for (int it = 0; it < 8; it++) {
                int rr = it * 8 + (lane >> 3);
                u32x4 val = *reinterpret_cast<const u32x4*>(ep + rr * 72 + (lane & 7) * 8);
                size_t grow = (size_t)(bm * GBM_ + wm2 * 128 + half * 64 + rr);
                *reinterpret_cast<u32x4*>(
                    C + grow * C_ + bn * GBN_ + wn4 * 64 + (lane & 7) * 8) = val;
            }
            asm volatile("s_waitcnt vmcnt(0) lgkmcnt(0)" ::: "memory");
        }
    } else {
        // MODE 2: bf16 PKT. Per-wave LDS patch [64 cols][16 chunks of 8 rows],
        // chunk XOR-swizzled by col. Each store instr writes one FULL 1 KB
        // packed tile (64 lanes x 16B contiguous).
        u16* ep = lds + w * 8192;
        #pragma unroll
        for (int mi = 0; mi < 8; mi++) {
            const int chunk = mi * 2 + (quad >> 1);
            const int rsub = (quad & 1) * 4;
            #pragma unroll
            for (int ni = 0; ni < 4; ni++) {
                const int col = ni * 16 + r16;
                u16* p = ep + col * 128 + ((chunk ^ col) & 15) * 8 + rsub;
                p[0] = f2b(acc[mi][ni][0]);
                p[1] = f2b(acc[mi][ni][1]);
                p[2] = f2b(acc[mi][ni][2]);
                p[3] = f2b(acc[mi][ni][3]);
            }
        }
        asm volatile("s_waitcnt lgkmcnt(0)" ::: "memory");
        __builtin_amdgcn_sched_barrier(0);
        u16* C = (u16*)Cc;
        const int cl = lane >> 2, ch4 = lane & 3;
        const int gc0 = bn * 16 + wn4 * 4;       // c-group base (c>>4)
        const int tt0 = bm * 8 + wm2 * 4;        // t-tile base (t>>5)
        #pragma unroll
        for (int it = 0; it < 16; it++) {
            const int col_l = (it & 3) * 16 + cl;
            const int chunk = (it >> 2) * 4 + ch4;
            u32x4 val = *reinterpret_cast<const u32x4*>(
                ep + col_l * 128 + ((chunk ^ col_l) & 15) * 8);
            const size_t tile = (size_t)(gc0 + (it & 3)) * 512 + tt0 + (it >> 2);
            *reinterpret_cast<u32x4*>(C + tile * 512 + cl * 32 + ch4 * 8) = val;
        }
    }
}

// Merged r/k/v GEMMs: one launch, 768 blocks (3 segments of 256).
// Removes 2 full-grid sync points; CU finishing its r-block starts a
// k-block immediately. Segment base 256 ≡ 0 mod 8 keeps co-XCD A-mapping.
__global__ __launch_bounds__(512, 2) void gemm3_kernel(
    const u16* __restrict__ xr, const u16* __restrict__ xk, const u16* __restrict__ xv,
    const u16* __restrict__ wtb, u16* __restrict__ rb,
    u16* __restrict__ kbT, u16* __restrict__ vbT)
{
    extern __shared__ __align__(16) u16 lds[];
    const int id = blockIdx.x;
    const int seg = id >> 8, lid = id & 255;
    if (seg == 0)      gemm_core<1>(lds, xr, wtb,           rb,  lid);
    else if (seg == 1) gemm_core<2>(lds, xk, wtb + 1048576, kbT, lid);
    else               gemm_core<2>(lds, xv, wtb + 2097152, vbT, lid);
}

__global__ __launch_bounds__(512, 2) void gemm_out_kernel(
    const u16* __restrict__ ygn, const u16* __restrict__ wob, float* __restrict__ out)
{
    extern __shared__ __align__(16) u16 lds[];
    gemm_core<0>(lds, ygn, wob, out, blockIdx.x);
}

// ---------------- K3: fused P = v^T k + decay scan (3-buffer ring) ----------
// PKT inputs. 256 blocks (b,h,m-half) x 512 threads. LDS 144 KB = 3 x 48 KB.
// 2-deep prefetch, raw barriers, counted vmcnt(6): KSTG(j)'s 6 own-wave glds
// retired at iter j's wait while KSTG(j+1)'s 6 stay in flight (~full
// iteration of slack); queue never drains mid-loop.
#define KVS_LDS_BYTES 147456

__global__ __launch_bounds__(512) void kvscan_kernel(
    const u16* __restrict__ kT, const u16* __restrict__ vT,
    const float* __restrict__ td, u16* __restrict__ stT)
{
    extern __shared__ __align__(16) u16 klds[];
    const int bm2 = blockIdx.x;            // bh*2 + mh
    const int mh = bm2 & 1, bh = bm2 >> 1;
    const int h = bh & (H_ - 1), b = bh >> 4;
    const float wdec = expf(-expf(td[h]));
    const int tid = threadIdx.x, lane = tid & 63, w = tid >> 6;
    const int r16 = lane & 15, quad = lane >> 4;
    const int cgn = w >> 1;                // n-group 0..3 (16 rows)
    const int ck  = w & 1;                 // m-sub 0..1 (16 cols)
    const int tt0 = b * 64;                // t-tile base for this batch
    const int loff = r16 * 32 + quad * 8;  // lane offset within a 1KB tile

    // stage chunk jj into ring slot jj%3: 48 x 1KB tiles, 6 glds/thread
#define KSTG(jj) do {                                                         \
    u16* db_ = klds + ((jj) % 3) * 24576;                                     \
    _Pragma("unroll")                                                         \
    for (int q = 0; q < 6; q++) {                                             \
        const int tau = w * 6 + q;                                            \
        const u16* src;                                                       \
        if (tau < 32)                                                         \
            src = vT + ((size_t)(h * 4 + (tau >> 3)) * 512 +                  \
                        tt0 + (jj) * 8 + (tau & 7)) * 512;                    \
        else                                                                  \
            src = kT + ((size_t)(h * 4 + mh * 2 + ((tau - 32) >> 3)) * 512 +  \
                        tt0 + (jj) * 8 + ((tau - 32) & 7)) * 512;             \
        glds16(src + (size_t)lane * 8, db_ + tau * 512);                      \
    }                                                                         \
} while (0)

    KSTG(0);
    KSTG(1);

    f32x4 st = f32x4{0.f, 0.f, 0.f, 0.f};
    for (int j = 0; j < NC_; ++j) {
        if (j + 1 < NC_) asm volatile("s_waitcnt vmcnt(6)" ::: "memory");
        else             asm volatile("s_waitcnt vmcnt(0)" ::: "memory");
        asm volatile("" ::: "memory");
        __builtin_amdgcn_s_barrier();
        asm volatile("" ::: "memory");
        // slot (j+2)%3 == (j-1)%3: its readers finished before this barrier
        if (j + 2 < NC_) KSTG(j + 2);
        const u16* bb = klds + (j % 3) * 24576;
        f32x4 acc = f32x4{0.f, 0.f, 0.f, 0.f};
        #pragma unroll
        for (int ks = 0; ks < 8; ks++) {
            s16x8 fa = *reinterpret_cast<const s16x8*>(
                bb + (cgn * 8 + ks) * 512 + loff);
            s16x8 fb = *reinterpret_cast<const s16x8*>(
                bb + (32 + ck * 8 + ks) * 512 + loff);
            acc = __builtin_amdgcn_mfma_f32_16x16x32_bf16(fa, fb, acc, 0, 0, 0);
        }
        st = (st + acc) * wdec;
        u16* out = stT + ((size_t)bh * NC_ + j) * 4096;
        #pragma unroll
        for (int i = 0; i < 4; i++)
            out[(cgn * 16 + quad * 4 + i) * HS_ + mh * 32 + ck * 16 + r16] =
                f2b(st[i]);
    }
#undef KSTG
}

// ---------------- K4: y = r @ state (MFMA), fused GroupNorm ----------------
__global__ __launch_bounds__(256) void rstate_gn_kernel(
    const u16* __restrict__ r, const u16* __restrict__ stT,
    const float* __restrict__ gnw, const float* __restrict__ gnb, u16* __restrict__ ygn)
{
    int blk = blockIdx.x;      // bh*NC + c
    int c  = blk & (NC_ - 1);
    int bh = blk >> 3;
    int h = bh & (H_ - 1);
    int b = bh >> 4;
    __shared__ __align__(16) u16 sT[HS_ * 72];   // pitch 72 u16
    int tid = threadIdx.x, lane = tid & 63, wave = tid >> 6;
    int r16 = lane & 15, quad = lane >> 4;

    const u16* sg = stT + (size_t)blk * (HS_ * HS_);
    for (int i = tid; i < 512; i += 256) {
        int n = i >> 3, c8 = (i & 7) * 8;
        *reinterpret_cast<u32x4*>(&sT[n * 72 + c8]) =
            *reinterpret_cast<const u32x4*>(sg + n * HS_ + c8);
    }
    __syncthreads();

    size_t rowBase = (size_t)(b * T_ + c * CHUNK_ + wave * 64);
    f32x4 acc[4][4];
    #pragma unroll
    for (int mi = 0; mi < 4; mi++)
        #pragma unroll
        for (int ni = 0; ni < 4; ni++)
            acc[mi][ni] = f32x4{0.f, 0.f, 0.f, 0.f};

    #pragma unroll
    for (int ks = 0; ks < 2; ks++) {
        int kb = ks * 32 + quad * 8;
        s16x8 fa[4], fb[4];
        #pragma unroll
        for (int mi = 0; mi < 4; mi++)
            fa[mi] = *reinterpret_cast<const s16x8*>(
                r + (rowBase + mi * 16 + r16) * C_ + h * HS_ + kb);
        #pragma unroll
        for (int ni = 0; ni < 4; ni++)
            fb[ni] = *reinterpret_cast<const s16x8*>(&sT[(ni * 16 + r16) * 72 + kb]);
        #pragma unroll
        for (int mi = 0; mi < 4; mi++)
            #pragma unroll
            for (int ni = 0; ni < 4; ni++)
                acc[mi][ni] = __builtin_amdgcn_mfma_f32_16x16x32_bf16(fa[mi], fb[ni], acc[mi][ni], 0, 0, 0);
    }

    float gwv[4], gbv[4];
    #pragma unroll
    for (int ni = 0; ni < 4; ni++) {
        int col = ni * 16 + r16;
        gwv[ni] = gnw[h * HS_ + col];
        gbv[ni] = gnb[h * HS_ + col];
    }
    #pragma unroll
    for (int mi = 0; mi < 4; mi++) {
        float s1[4], s2[4];
        #pragma unroll
        for (int i = 0; i < 4; i++) {
            float s = 0.f, ss = 0.f;
            #pragma unroll
            for (int ni = 0; ni < 4; ni++) {
                float v = acc[mi][ni][i];
                s += v; ss += v * v;
            }
            s1[i] = s; s2[i] = ss;
        }
        #pragma unroll
        for (int d = 1; d < 16; d <<= 1) {
            #pragma unroll
            for (int i = 0; i < 4; i++) {
                s1[i] += __shfl_xor(s1[i], d);
                s2[i] += __shfl_xor(s2[i], d);
            }
        }
        #pragma unroll
        for (int i = 0; i < 4; i++) {
            float mu = s1[i] * (1.f / 64.f);
            float var = s2[i] * (1.f / 64.f) - mu * mu;
            float sc = rsqrtf(var + 1e-5f);
            size_t ob = (rowBase + mi * 16 + quad * 4 + i) * C_ + h * HS_;
            #pragma unroll
            for (int ni = 0; ni < 4; ni++)
                ygn[ob + ni * 16 + r16] = f2b((acc[mi][ni][i] - mu) * sc * gwv[ni] + gbv[ni]);
        }
    }
}

// ---------------------------------------------------------------------------
extern "C" void kernel_launch(void* const* d_in, const int* in_sizes, int n_in,
                              void* d_out, int out_size, void* d_ws, size_t ws_size,
                              hipStream_t stream) {
    const float* x    = (const float*)d_in[0];
    const float* vol  = (const float*)d_in[1];
    const float* Wvol = (const float*)d_in[2];
    const float* bvol = (const float*)d_in[3];
    const float* mk   = (const float*)d_in[4];
    const float* mv   = (const float*)d_in[5];
    const float* mr   = (const float*)d_in[6];
    const float* td   = (const float*)d_in[7];
    const float* Wk   = (const float*)d_in[8];
    const float* Wv   = (const float*)d_in[9];
    const float* Wr   = (const float*)d_in[10];
    const float* Wo   = (const float*)d_in[11];
    const float* gnw  = (const float*)d_in[12];
    const float* gnb  = (const float*)d_in[13];
    float* out = (float*)d_out;

    // one-time: allow big dynamic LDS (host-side, capture-safe)
    static bool init_attr = []() {
        hipFuncSetAttribute(reinterpret_cast<const void*>(gemm3_kernel),
                            hipFuncAttributeMaxDynamicSharedMemorySize, GEMM_LDS_BYTES);
        hipFuncSetAttribute(reinterpret_cast<const void*>(gemm_out_kernel),
                            hipFuncAttributeMaxDynamicSharedMemorySize, GEMM_LDS_BYTES);
        hipFuncSetAttribute(reinterpret_cast<const void*>(kvscan_kernel),
                            hipFuncAttributeMaxDynamicSharedMemorySize, KVS_LDS_BYTES);
        return true;
    }();
    (void)init_attr;

    char* ws = (char*)d_ws;
    const size_t SLOT = (size_t)B_ * T_ * C_ * 2;   // 33,554,432 B
    // s0: xr -> kbT -> ygn ; s1: xk -> vbT ; s2: xv -> stT ; s3: rb
    u16* xr = (u16*)(ws + 0 * SLOT);
    u16* xk = (u16*)(ws + 1 * SLOT);
    u16* xv = (u16*)(ws + 2 * SLOT);
    u16* rb = (u16*)(ws + 3 * SLOT);
    u16* kbT = (u16*)(ws + 0 * SLOT);                    // PKT packed
    u16* vbT = (u16*)(ws + 1 * SLOT);                    // PKT packed
    u16* stT = (u16*)(ws + 2 * SLOT + SLOT / 2);         // 8.4 MB
    u16* ygn = (u16*)(ws + 0 * SLOT);
    u16* wtb = (u16*)(ws + 4 * SLOT);                    // 4 bf16 weight mats
    u16* wob = wtb + (size_t)3 * C_ * C_;

    // prep: blocks [0,2048) mix, [2048,4096) weight cvt (order: Wr,Wk,Wv,Wo)
    prep_kernel<<<dim3(4096), dim3(256), 0, stream>>>(
        x, vol, Wvol, bvol, mk, mv, mr, xk, xv, xr, Wr, Wk, Wv, Wo, wtb);

    // merged r/k/v GEMMs (768 blocks)
    gemm3_kernel<<<dim3(768), dim3(512), GEMM_LDS_BYTES, stream>>>(
        xr, xk, xv, wtb, rb, kbT, vbT);

    // fused kv-outer + decay scan: 256 blocks (b,h,m-half), 512 threads
    kvscan_kernel<<<dim3(B_ * H_ * 2), dim3(512), KVS_LDS_BYTES, stream>>>(kbT, vbT, td, stT);

    rstate_gn_kernel<<<dim3(B_ * H_ * NC_), dim3(256), 0, stream>>>(rb, stT, gnw, gnb, ygn);

    gemm_out_kernel<<<dim3(256), dim3(512), GEMM_LDS_BYTES, stream>>>(ygn, wob, out);
}